// Round 6
// baseline (83.332 us; speedup 1.0000x reference)
//
#include <hip/hip_runtime.h>

// TorchVQC: 8-qubit statevector, B=16384, D=256, fp32 complex.
// Layout: 4 batch elements per wave (16 lanes each), 16 amplitudes per lane.
// Stored index s = (j<<4) | lane16 : lane16 = s[3:0], register j = s[7:4].
// CNOTs folded away via GF(2) relabeling (v/u tables verified R2-R4).
// R6: SoA packing — state held as R[8],I[8] f2-pairs over (j,j+1); gate core
//     is pure elementwise -> v_pk_fma_f32 with NO half-swizzles (4 insts/amp).
//     NOTE (R5 lesson): op_sel on v_pk_*_f32 is NOT honored on gfx950 HW
//     (assembles, computes garbage). Only neg modifiers work on packed f32.

using f2 = __attribute__((ext_vector_type(2))) float;  // element pair

__device__ __forceinline__ f2 pkfma(f2 a, f2 b, f2 c) {
    return __builtin_elementwise_fma(a, b, c);
}

// complex scalar helpers (f2 = one complex number (re,im)) — prep paths only
__device__ __forceinline__ f2 cmul2(f2 w, f2 z) {
    f2 r;
    r.x = w.x * z.x - w.y * z.y;
    r.y = w.x * z.y + w.y * z.x;
    return r;
}
__device__ __forceinline__ f2 cmadd(f2 acc, f2 w, f2 z) {
    acc.x += w.x * z.x - w.y * z.y;
    acc.y += w.x * z.y + w.y * z.x;
    return acc;
}

__device__ __forceinline__ f2 shflx(f2 v, int m) {
    f2 r; r.x = __shfl_xor(v.x, m, 64); r.y = __shfl_xor(v.y, m, 64); return r;
}

// selected encoding-column entry: hi ? (s*cp, s*sp) : (c*cp, -c*sp)
__device__ __forceinline__ f2 enc_sel(float t, float p, bool hi) {
    float s_, c_, sp_, cp_;
    __sincosf(t * 0.5f, &s_, &c_);
    __sincosf(p * 0.5f, &sp_, &cp_);
    const float m = hi ? s_ : c_;
    f2 r; r.x = m * cp_; r.y = hi ? m * sp_ : -m * sp_;
    return r;
}

// new = a_c * x + b_c * y (complex, packed over 2 amplitudes)
#define UPD(c, xR, xI, yR, yI, oR, oI) do {                \
    f2 t_ = Ar[c] * (xR);                                  \
    t_ = pkfma(-Ai[c], (xI), t_);                          \
    t_ = pkfma( Br[c], (yR), t_);                          \
    const f2 nR_ = pkfma(-Bi[c], (yI), t_);                \
    f2 u_ = Ar[c] * (xI);                                  \
    u_ = pkfma( Ai[c], (xR), u_);                          \
    u_ = pkfma( Br[c], (yI), u_);                          \
    (oI) = pkfma( Bi[c], (yR), u_);                        \
    (oR) = nR_;                                            \
} while (0)

// Gate on true-qubit under relabeling. v = (VREG<<4)|VLANE toggle, u = sign row.
// c(s) = par(lane&ULANE) ^ par(j&UREG); new[s] = a_{c} s[s] + b_{c} s[s^v].
// State packs: R[m]/I[m] hold amps j=2m (lo), j=2m+1 (hi).
template<int VREG, int VLANE, int UREG, int ULANE>
__device__ __forceinline__ void gateS(f2 (&R)[8], f2 (&I)[8], int lane16,
                                      f2 g00, f2 g01, f2 g10, f2 g11)
{
    f2 a0, b0, a1, b1;
    if constexpr (ULANE != 0) {
        const bool lp = (__popc(lane16 & ULANE) & 1) != 0;
        a0 = lp ? g11 : g00;  b0 = lp ? g10 : g01;
        a1 = lp ? g00 : g11;  b1 = lp ? g01 : g10;
    } else {
        a0 = g00; b0 = g01; a1 = g11; b1 = g10;
    }
    // packed coefficient variants: index = c(j=2m); mix handles c differing
    // between lo/hi amp of a pack (UREG bit0).
    constexpr bool mix = (UREG & 1) != 0;
    f2 Ar[2], Ai[2], Br[2], Bi[2];
    if constexpr (mix) {
        Ar[0]=(f2){a0.x,a1.x}; Ai[0]=(f2){a0.y,a1.y};
        Br[0]=(f2){b0.x,b1.x}; Bi[0]=(f2){b0.y,b1.y};
        Ar[1]=(f2){a1.x,a0.x}; Ai[1]=(f2){a1.y,a0.y};
        Br[1]=(f2){b1.x,b0.x}; Bi[1]=(f2){b1.y,b0.y};
    } else {
        Ar[0]=(f2){a0.x,a0.x}; Ai[0]=(f2){a0.y,a0.y};
        Br[0]=(f2){b0.x,b0.x}; Bi[0]=(f2){b0.y,b0.y};
        Ar[1]=(f2){a1.x,a1.x}; Ai[1]=(f2){a1.y,a1.y};
        Br[1]=(f2){b1.x,b1.x}; Bi[1]=(f2){b1.y,b1.y};
    }
    constexpr int PM  = VREG >> 1;          // pack-index toggle
    constexpr int UH  = UREG >> 1;          // pack-parity mask
    constexpr bool SW = (VREG & 1) != 0;    // partner half-swapped

    if constexpr (VREG == 0) {              // pure lane pairing
        #pragma unroll
        for (int m = 0; m < 8; ++m) {
            const int c = __builtin_popcount(m & UH) & 1;
            const f2 pR = shflx(R[m], VLANE), pI = shflx(I[m], VLANE);
            UPD(c, R[m], I[m], pR, pI, R[m], I[m]);
        }
    } else if constexpr (VLANE == 0 && !SW) {   // register pairing, pack<->pack
        constexpr int pivot = PM & (-PM);
        #pragma unroll
        for (int m = 0; m < 8; ++m) {
            if (m & pivot) continue;
            const int m2 = m ^ PM;
            const int c  = __builtin_popcount(m  & UH) & 1;
            const int c2 = __builtin_popcount(m2 & UH) & 1;
            const f2 xR=R[m], xI=I[m], yR=R[m2], yI=I[m2];
            UPD(c,  xR, xI, yR, yI, R[m],  I[m]);
            UPD(c2, yR, yI, xR, xI, R[m2], I[m2]);
        }
    } else if constexpr (VLANE == 0 && SW && PM == 0) {  // swap within pack
        #pragma unroll
        for (int m = 0; m < 8; ++m) {
            const int c = __builtin_popcount(m & UH) & 1;
            const f2 xR=R[m], xI=I[m];
            const f2 yR=(f2){xR.y,xR.x}, yI=(f2){xI.y,xI.x};
            UPD(c, xR, xI, yR, yI, R[m], I[m]);
        }
    } else if constexpr (VLANE == 0 && SW) {    // swapped partner pack
        constexpr int pivot = PM & (-PM);
        #pragma unroll
        for (int m = 0; m < 8; ++m) {
            if (m & pivot) continue;
            const int m2 = m ^ PM;
            const int c  = __builtin_popcount(m  & UH) & 1;
            const int c2 = __builtin_popcount(m2 & UH) & 1;
            const f2 xR=R[m], xI=I[m], yR=R[m2], yI=I[m2];
            const f2 ysR=(f2){yR.y,yR.x}, ysI=(f2){yI.y,yI.x};
            const f2 xsR=(f2){xR.y,xR.x}, xsI=(f2){xI.y,xI.x};
            UPD(c,  xR, xI, ysR, ysI, R[m],  I[m]);
            UPD(c2, yR, yI, xsR, xsI, R[m2], I[m2]);
        }
    } else if constexpr (SW) {                  // lane + swap (PM==0 case used)
        #pragma unroll
        for (int m = 0; m < 8; ++m) {
            const int c = __builtin_popcount(m & UH) & 1;
            const f2 pR = shflx(R[m], VLANE), pI = shflx(I[m], VLANE);
            const f2 sR=(f2){pR.y,pR.x}, sI=(f2){pI.y,pI.x};
            UPD(c, R[m], I[m], sR, sI, R[m], I[m]);
        }
    } else {                                    // lane + register pack pairing
        constexpr int pivot = PM & (-PM);
        #pragma unroll
        for (int m = 0; m < 8; ++m) {
            if (m & pivot) continue;
            const int m2 = m ^ PM;
            const int c  = __builtin_popcount(m  & UH) & 1;
            const int c2 = __builtin_popcount(m2 & UH) & 1;
            const f2 p1R = shflx(R[m2], VLANE), p1I = shflx(I[m2], VLANE);
            const f2 p2R = shflx(R[m],  VLANE), p2I = shflx(I[m],  VLANE);
            UPD(c,  R[m],  I[m],  p1R, p1I, R[m],  I[m]);
            UPD(c2, R[m2], I[m2], p2R, p2I, R[m2], I[m2]);
        }
    }
}

// layer-0 Rot: precomputed matrix, uniform load from ws
#define ROT0(K, VR, VL, UR, UL) do {                                    \
    const float* g_ = gates + (K)*8;                                    \
    const f2 R00={g_[0],g_[1]}, R01={g_[2],g_[3]};                      \
    const f2 R10={g_[4],g_[5]}, R11={g_[6],g_[7]};                      \
    gateS<VR, VL, UR, UL>(R, I, lane16, R00, R01, R10, R11);            \
} while (0)

// fused: F = Rot(1,K) . Renc(K)   (Renc = RZ(ph/2) RY(th/2), quarter angles)
#define FUSED(K, VR, VL, UR, UL) do {                                   \
    const float* g_ = gates + (8 + (K))*8;                              \
    const f2 R00={g_[0],g_[1]}, R01={g_[2],g_[3]};                      \
    const f2 R10={g_[4],g_[5]}, R11={g_[6],g_[7]};                      \
    float c_, s_, cp_, sp_;                                             \
    __sincosf(th[K] * 0.25f, &s_, &c_);                                 \
    __sincosf(ph[K] * 0.25f, &sp_, &cp_);                               \
    const f2 E00={ c_*cp_, -c_*sp_}, E01={-s_*cp_,  s_*sp_};            \
    const f2 E10={ s_*cp_,  s_*sp_}, E11={ c_*cp_,  c_*sp_};            \
    const f2 F00 = cmadd(cmul2(R00, E00), R01, E10);                    \
    const f2 F01 = cmadd(cmul2(R00, E01), R01, E11);                    \
    const f2 F10 = cmadd(cmul2(R10, E00), R11, E10);                    \
    const f2 F11 = cmadd(cmul2(R10, E01), R11, E11);                    \
    gateS<VR, VL, UR, UL>(R, I, lane16, F00, F01, F10, F11);            \
} while (0)

// Rot = RZ(om)RY(th)RZ(ph): g00=c e^{-i(ph+om)/2}, g01=-s e^{+i(ph-om)/2},
// g10=s e^{-i(ph-om)/2}, g11=c e^{+i(ph+om)/2}. w is batch-independent.
__global__ __launch_bounds__(64) void prep_gates(const float* __restrict__ w,
                                                 float* __restrict__ g)
{
    const int t = threadIdx.x;
    if (t < 16) {
        const float wph = w[t*3+0], wth = w[t*3+1], wom = w[t*3+2];
        float c_, s_, ca_, sa_, cb_, sb_;
        __sincosf(wth * 0.5f, &s_, &c_);
        __sincosf(0.5f * (wph + wom), &sa_, &ca_);
        __sincosf(0.5f * (wph - wom), &sb_, &cb_);
        float* o = g + t * 8;
        o[0] =  c_*ca_;  o[1] = -c_*sa_;
        o[2] = -s_*cb_;  o[3] = -s_*sb_;
        o[4] =  s_*cb_;  o[5] = -s_*sb_;
        o[6] =  c_*ca_;  o[7] =  c_*sa_;
    }
}

__global__ __launch_bounds__(64, 4) void vqc_kernel(
    const float* __restrict__ theta,   // [B,8]
    const float* __restrict__ phi,     // [B,8]
    const float* __restrict__ jup,     // [B,28]
    const float* __restrict__ gates,   // [16,8] precomputed Rot matrices
    float* __restrict__ out,           // [B,8]
    int Btot)
{
    const int wid    = blockIdx.x;         // one wave per block
    const int lane   = threadIdx.x & 63;
    const int lane16 = lane & 15;
    const int bq     = wid * 4 + (lane >> 4);
    const int b      = bq < Btot ? bq : Btot - 1;   // clamp for loads

    float th[8], ph[8];
    {
        const float4* t4 = reinterpret_cast<const float4*>(theta + (size_t)b * 8);
        const float4* p4 = reinterpret_cast<const float4*>(phi   + (size_t)b * 8);
        const float4 a = t4[0], c = t4[1], d = p4[0], e = p4[1];
        th[0]=a.x; th[1]=a.y; th[2]=a.z; th[3]=a.w;
        th[4]=c.x; th[5]=c.y; th[6]=c.z; th[7]=c.w;
        ph[0]=d.x; ph[1]=d.y; ph[2]=d.z; ph[3]=d.w;
        ph[4]=e.x; ph[5]=e.y; ph[6]=e.z; ph[7]=e.w;
    }

    // ---- lane-side encoding product over qubits 4..7 ----
    f2 P = enc_sel(th[4], ph[4], (lane16 & 8) != 0);
    P = cmul2(P, enc_sel(th[5], ph[5], (lane16 & 4) != 0));
    P = cmul2(P, enc_sel(th[6], ph[6], (lane16 & 2) != 0));
    P = cmul2(P, enc_sel(th[7], ph[7], (lane16 & 1) != 0));

    // ---- register-side partial products m01 (qubits 0,1), m23 (qubits 2,3) ----
    f2 m01[4], m23[4];
    {
        float s0, c0, sp0, cp0, s1, c1, sp1, cp1;
        __sincosf(th[0]*0.5f, &s0, &c0); __sincosf(ph[0]*0.5f, &sp0, &cp0);
        __sincosf(th[1]*0.5f, &s1, &c1); __sincosf(ph[1]*0.5f, &sp1, &cp1);
        const f2 A0={c0*cp0,-c0*sp0}, A1={s0*cp0,s0*sp0};
        const f2 B0={c1*cp1,-c1*sp1}, B1={s1*cp1,s1*sp1};
        #pragma unroll
        for (int a = 0; a < 4; ++a)
            m01[a] = cmul2((a & 2) ? A1 : A0, (a & 1) ? B1 : B0);
        __sincosf(th[2]*0.5f, &s0, &c0); __sincosf(ph[2]*0.5f, &sp0, &cp0);
        __sincosf(th[3]*0.5f, &s1, &c1); __sincosf(ph[3]*0.5f, &sp1, &cp1);
        const f2 C0={c0*cp0,-c0*sp0}, C1={s0*cp0,s0*sp0};
        const f2 D0={c1*cp1,-c1*sp1}, D1={s1*cp1,s1*sp1};
        #pragma unroll
        for (int a = 0; a < 4; ++a)
            m23[a] = cmul2((a & 2) ? C1 : C0, (a & 1) ? D1 : D0);
    }

    // ---- IsingZZ reduction: J[28] -> c01..c23, Q0..Q3, LL ----
    float c01, c02, c03, c12, c13, c23, Q0, Q1, Q2, Q3, LL;
    {
        const float4* J4 = reinterpret_cast<const float4*>(jup + (size_t)b * 28);
        const float z4 = (lane16 & 8) ? -1.f : 1.f;
        const float z5 = (lane16 & 4) ? -1.f : 1.f;
        const float z6 = (lane16 & 2) ? -1.f : 1.f;
        const float z7 = (lane16 & 1) ? -1.f : 1.f;
        const float4 x0 = J4[0], x1 = J4[1], x2 = J4[2], x3 = J4[3];
        const float4 x4 = J4[4], x5 = J4[5], x6 = J4[6];
        c01 = x0.x; c02 = x0.y; c03 = x0.z;
        Q0  = x0.w*z4 + x1.x*z5 + x1.y*z6 + x1.z*z7;
        c12 = x1.w; c13 = x2.x;
        Q1  = x2.y*z4 + x2.z*z5 + x2.w*z6 + x3.x*z7;
        c23 = x3.y;
        Q2  = x3.z*z4 + x3.w*z5 + x4.x*z6 + x4.y*z7;
        Q3  = x4.z*z4 + x4.w*z5 + x5.x*z6 + x5.y*z7;
        LL  = x5.z*(z4*z5) + x5.w*(z4*z6) + x6.x*(z4*z7)
            + x6.y*(z5*z6) + x6.z*(z5*z7) + x6.w*(z6*z7);
    }

    // ---- init amplitudes: product state x Ising phase, packed (j,j+1) ----
    f2 R[8], I[8];
    constexpr float HPI = 1.5707963267948966f;
    #pragma unroll
    for (int m = 0; m < 8; ++m) {
        f2 amp[2];
        #pragma unroll
        for (int h = 0; h < 2; ++h) {
            const int j = 2 * m + h;
            f2 u = cmul2(cmul2(m01[j >> 2], m23[j & 3]), P);
            float S = LL;
            S += ((__builtin_popcount(j & 0xC) & 1) ? -c01 : c01);
            S += ((__builtin_popcount(j & 0xA) & 1) ? -c02 : c02);
            S += ((__builtin_popcount(j & 0x9) & 1) ? -c03 : c03);
            S += ((__builtin_popcount(j & 0x6) & 1) ? -c12 : c12);
            S += ((__builtin_popcount(j & 0x5) & 1) ? -c13 : c13);
            S += ((__builtin_popcount(j & 0x3) & 1) ? -c23 : c23);
            S += ((j & 8) ? -Q0 : Q0);
            S += ((j & 4) ? -Q1 : Q1);
            S += ((j & 2) ? -Q2 : Q2);
            S += ((j & 1) ? -Q3 : Q3);
            float se, ce;
            __sincosf(-HPI * S, &se, &ce);
            amp[h] = cmul2(u, (f2){ce, se});
        }
        R[m] = (f2){amp[0].x, amp[1].x};
        I[m] = (f2){amp[0].y, amp[1].y};
    }

    // ---- layer-0 Rot gates (A = I): v = u = e_p, p = 7-k ----
    ROT0(0, 0x8, 0x0, 0x8, 0x0);
    ROT0(1, 0x4, 0x0, 0x4, 0x0);
    ROT0(2, 0x2, 0x0, 0x2, 0x0);
    ROT0(3, 0x1, 0x0, 0x1, 0x0);
    ROT0(4, 0x0, 0x8, 0x0, 0x8);
    ROT0(5, 0x0, 0x4, 0x0, 0x4);
    ROT0(6, 0x0, 0x2, 0x0, 0x2);
    ROT0(7, 0x0, 0x1, 0x0, 0x1);

    // ---- layer-0 CNOT ring folded into relabeling; RENC(k)+ROT(1,k) fused ----
    FUSED(0, 0xC, 0x0, 0x7, 0xF);
    FUSED(1, 0x6, 0x0, 0xC, 0x0);
    FUSED(2, 0x3, 0x0, 0xE, 0x0);
    FUSED(3, 0x1, 0x8, 0xF, 0x0);
    FUSED(4, 0x0, 0xC, 0xF, 0x8);
    FUSED(5, 0x0, 0x6, 0xF, 0xC);
    FUSED(6, 0x0, 0x3, 0xF, 0xE);
    FUSED(7, 0xC, 0x1, 0xF, 0xF);

    // layer-1 CNOT ring folded into readout signs (final A rows, verified R2)
    // ---- readout: probs (packed), 16-point WHT, lane signs ----
    float p[16];
    #pragma unroll
    for (int m = 0; m < 8; ++m) {
        const f2 t = pkfma(I[m], I[m], R[m] * R[m]);
        p[2*m]   = t.x;
        p[2*m+1] = t.y;
    }
    #pragma unroll
    for (int st = 1; st < 16; st <<= 1) {
        #pragma unroll
        for (int j = 0; j < 16; ++j) {
            if ((j & st) != 0) continue;
            const float a = p[j], bb = p[j | st];
            p[j] = a + bb;  p[j | st] = a - bb;
        }
    }
    float o[8];
    o[0] = (__popc(lane16 & 0x6) & 1) ? -p[0xE] : p[0xE];
    o[1] = (__popc(lane16 & 0x3) & 1) ? -p[0xF] : p[0xF];
    o[2] = (__popc(lane16 & 0xF) & 1) ? -p[0x9] : p[0x9];
    o[3] = p[0x3];
    o[4] = (__popc(lane16 & 0x7) & 1) ? -p[0x6] : p[0x6];
    o[5] = (__popc(lane16 & 0xC) & 1) ? -p[0xC] : p[0xC];
    o[6] = (__popc(lane16 & 0x9) & 1) ? -p[0x9] : p[0x9];
    o[7] = (__popc(lane16 & 0x3) & 1) ? -p[0x3] : p[0x3];

    #pragma unroll
    for (int m = 1; m <= 8; m <<= 1) {
        #pragma unroll
        for (int q = 0; q < 8; ++q) o[q] += __shfl_xor(o[q], m, 64);
    }

    if (lane16 == 0 && bq < Btot) {
        float4* op = reinterpret_cast<float4*>(out + (size_t)bq * 8);
        op[0] = make_float4(o[0], o[1], o[2], o[3]);
        op[1] = make_float4(o[4], o[5], o[6], o[7]);
    }
}

extern "C" void kernel_launch(void* const* d_in, const int* in_sizes, int n_in,
                              void* d_out, int out_size, void* d_ws, size_t ws_size,
                              hipStream_t stream) {
    const float* theta = (const float*)d_in[0];
    const float* phi   = (const float*)d_in[1];
    const float* jup   = (const float*)d_in[2];
    const float* w     = (const float*)d_in[3];
    float* out   = (float*)d_out;
    float* gates = (float*)d_ws;                 // 16 gates x 8 floats = 512 B

    const int B = in_sizes[0] / 8;               // 16384
    hipLaunchKernelGGL(prep_gates, dim3(1), dim3(64), 0, stream, w, gates);

    const int blocks = (B + 3) / 4;              // 4096: one wave / block
    hipLaunchKernelGGL(vqc_kernel, dim3(blocks), dim3(64), 0, stream,
                       theta, phi, jup, gates, out, B);
}

// Round 7
// 81.896 us; speedup vs baseline: 1.0175x; 1.0175x over previous
//
#include <hip/hip_runtime.h>

// TorchVQC: 8-qubit statevector, B=16384, D=256, fp32 complex.
// Layout: 4 batch elements per wave (16 lanes each), 16 amplitudes per lane.
// Stored index s = (j<<4) | lane16 : lane16 = s[3:0], register j = s[7:4].
// CNOTs folded away via GF(2) relabeling (v/u tables verified R2-R4).
// R7: SU(2) sign-folding. All gates satisfy g11=conj(g00), g10=-conj(g01),
//     so coefficient selection becomes: runtime lane-parity sign (one XOR on
//     g00i / g01r per gate) + compile-time per-amp sign folded into fma neg
//     modifiers. Gate core = 128 FMA + 2 XOR, no cndmask/mov setup.
//     (R5 lesson kept: no op_sel on v_pk_*_f32 — not honored on gfx950.)

using f2 = __attribute__((ext_vector_type(2))) float;  // (re, im)

// scalar complex helpers (prep paths only)
__device__ __forceinline__ f2 cmul2(f2 w, f2 z) {
    f2 r;
    r.x = w.x * z.x - w.y * z.y;
    r.y = w.x * z.y + w.y * z.x;
    return r;
}
__device__ __forceinline__ f2 cmadd(f2 acc, f2 w, f2 z) {
    acc.x += w.x * z.x - w.y * z.y;
    acc.y += w.x * z.y + w.y * z.x;
    return acc;
}

__device__ __forceinline__ f2 shflx(f2 v, int m) {
    f2 r; r.x = __shfl_xor(v.x, m, 64); r.y = __shfl_xor(v.y, m, 64); return r;
}

__device__ __forceinline__ float uxor(float f, unsigned u) {
    return __uint_as_float(__float_as_uint(f) ^ u);
}

// selected encoding-column entry: hi ? (s*cp, s*sp) : (c*cp, -c*sp)
__device__ __forceinline__ f2 enc_sel(float t, float p, bool hi) {
    float s_, c_, sp_, cp_;
    __sincosf(t * 0.5f, &s_, &c_);
    __sincosf(p * 0.5f, &sp_, &cp_);
    const float m = hi ? s_ : c_;
    f2 r; r.x = m * cp_; r.y = hi ? m * sp_ : -m * sp_;
    return r;
}

// SU(2) gate under relabeling. giP = g00i^signlane, brP = g01r^signlane.
// Per amp q with partner value w:  c(q) = par(q&UREG) (compile-time) ^ laneparity
//   new_r = g00r*q.r - (sigma*giP)*q.i + (sigma*brP)*w.r - g01i*w.i
//   new_i = g00r*q.i + (sigma*giP)*q.r + (sigma*brP)*w.i + g01i*w.r
// where sigma = +1 if par(q&UREG)==0 else -1 (folded into fma neg modifiers).
template<int VREG, int VLANE, int UREG>
__device__ __forceinline__ void gateU(f2 (&s)[16],
                                      float g00r, float giP, float brP, float g01i)
{
    if constexpr (VLANE == 0) {
        constexpr int pivot = VREG & (-VREG);
        #pragma unroll
        for (int j = 0; j < 16; ++j) {
            if ((j & pivot) != 0) continue;
            const int j2 = j ^ VREG;
            const f2 x = s[j], y = s[j2];
            {
                const bool n = (__builtin_popcount(j & UREG) & 1) != 0;
                const float gi = n ? -giP : giP, br = n ? -brP : brP;
                s[j].x = fmaf(-g01i, y.y, fmaf(br, y.x, fmaf(-gi, x.y, g00r * x.x)));
                s[j].y = fmaf( g01i, y.x, fmaf(br, y.y, fmaf( gi, x.x, g00r * x.y)));
            }
            {
                const bool n = (__builtin_popcount(j2 & UREG) & 1) != 0;
                const float gi = n ? -giP : giP, br = n ? -brP : brP;
                s[j2].x = fmaf(-g01i, x.y, fmaf(br, x.x, fmaf(-gi, y.y, g00r * y.x)));
                s[j2].y = fmaf( g01i, x.x, fmaf(br, x.y, fmaf( gi, y.x, g00r * y.y)));
            }
        }
    } else if constexpr (VREG == 0) {
        #pragma unroll
        for (int j = 0; j < 16; ++j) {
            const f2 w = shflx(s[j], VLANE);
            const f2 x = s[j];
            const bool n = (__builtin_popcount(j & UREG) & 1) != 0;
            const float gi = n ? -giP : giP, br = n ? -brP : brP;
            s[j].x = fmaf(-g01i, w.y, fmaf(br, w.x, fmaf(-gi, x.y, g00r * x.x)));
            s[j].y = fmaf( g01i, w.x, fmaf(br, w.y, fmaf( gi, x.x, g00r * x.y)));
        }
    } else {
        constexpr int pivot = VREG & (-VREG);
        #pragma unroll
        for (int j = 0; j < 16; ++j) {
            if ((j & pivot) != 0) continue;
            const int j2 = j ^ VREG;
            const f2 p1 = shflx(s[j2], VLANE);
            const f2 p2 = shflx(s[j],  VLANE);
            const f2 x = s[j], y = s[j2];
            {
                const bool n = (__builtin_popcount(j & UREG) & 1) != 0;
                const float gi = n ? -giP : giP, br = n ? -brP : brP;
                s[j].x = fmaf(-g01i, p1.y, fmaf(br, p1.x, fmaf(-gi, x.y, g00r * x.x)));
                s[j].y = fmaf( g01i, p1.x, fmaf(br, p1.y, fmaf( gi, x.x, g00r * x.y)));
            }
            {
                const bool n = (__builtin_popcount(j2 & UREG) & 1) != 0;
                const float gi = n ? -giP : giP, br = n ? -brP : brP;
                s[j2].x = fmaf(-g01i, p2.y, fmaf(br, p2.x, fmaf(-gi, y.y, g00r * y.x)));
                s[j2].y = fmaf( g01i, p2.x, fmaf(br, p2.y, fmaf( gi, y.x, g00r * y.y)));
            }
        }
    }
}

// layer-0 Rot: precomputed (g00,g01), uniform load from ws
#define ROT0(K, VR, VL, UR, SL) do {                                    \
    const float4 g_ = *reinterpret_cast<const float4*>(gates + (K)*4);  \
    gateU<VR, VL, UR>(s, g_.x, uxor(g_.y, SL), uxor(g_.z, SL), g_.w);   \
} while (0)

// fused: F = Rot(1,K) . Renc(K); only F00,F01 needed (SU(2))
#define FUSED(K, VR, VL, UR, SL) do {                                   \
    const float4 g_ = *reinterpret_cast<const float4*>(gates + (8+(K))*4); \
    const f2 R00 = {g_.x, g_.y}, R01 = {g_.z, g_.w};                    \
    float c_, s_, cp_, sp_;                                             \
    __sincosf(th[K] * 0.25f, &s_, &c_);                                 \
    __sincosf(ph[K] * 0.25f, &sp_, &cp_);                               \
    const f2 E00 = { c_*cp_, -c_*sp_}, E10 = { s_*cp_,  s_*sp_};        \
    const f2 E01 = {-s_*cp_,  s_*sp_}, E11 = { c_*cp_,  c_*sp_};        \
    const f2 F00 = cmadd(cmul2(R00, E00), R01, E10);                    \
    const f2 F01 = cmadd(cmul2(R00, E01), R01, E11);                    \
    gateU<VR, VL, UR>(s, F00.x, uxor(F00.y, SL), uxor(F01.x, SL), F01.y); \
} while (0)

// Rot = RZ(om)RY(th)RZ(ph): g00=c e^{-i(ph+om)/2}, g01=-s e^{+i(ph-om)/2}.
// SU(2): g11/g10 derived, not stored. w is batch-independent.
__global__ __launch_bounds__(64) void prep_gates(const float* __restrict__ w,
                                                 float* __restrict__ g)
{
    const int t = threadIdx.x;
    if (t < 16) {
        const float wph = w[t*3+0], wth = w[t*3+1], wom = w[t*3+2];
        float c_, s_, ca_, sa_, cb_, sb_;
        __sincosf(wth * 0.5f, &s_, &c_);
        __sincosf(0.5f * (wph + wom), &sa_, &ca_);
        __sincosf(0.5f * (wph - wom), &sb_, &cb_);
        float* o = g + t * 4;
        o[0] =  c_*ca_;  o[1] = -c_*sa_;   // g00
        o[2] = -s_*cb_;  o[3] = -s_*sb_;   // g01
    }
}

__global__ __launch_bounds__(64, 4) void vqc_kernel(
    const float* __restrict__ theta,   // [B,8]
    const float* __restrict__ phi,     // [B,8]
    const float* __restrict__ jup,     // [B,28]
    const float* __restrict__ gates,   // [16,4] precomputed (g00,g01)
    float* __restrict__ out,           // [B,8]
    int Btot)
{
    const int wid    = blockIdx.x;         // one wave per block
    const int lane   = threadIdx.x & 63;
    const int lane16 = lane & 15;
    const int bq     = wid * 4 + (lane >> 4);
    const int b      = bq < Btot ? bq : Btot - 1;   // clamp for loads

    float th[8], ph[8];
    {
        const float4* t4 = reinterpret_cast<const float4*>(theta + (size_t)b * 8);
        const float4* p4 = reinterpret_cast<const float4*>(phi   + (size_t)b * 8);
        const float4 a = t4[0], c = t4[1], d = p4[0], e = p4[1];
        th[0]=a.x; th[1]=a.y; th[2]=a.z; th[3]=a.w;
        th[4]=c.x; th[5]=c.y; th[6]=c.z; th[7]=c.w;
        ph[0]=d.x; ph[1]=d.y; ph[2]=d.z; ph[3]=d.w;
        ph[4]=e.x; ph[5]=e.y; ph[6]=e.z; ph[7]=e.w;
    }

    // lane-parity sign words (bit31) for ULANE masks used by the gate table
    const unsigned s8 = (unsigned)(lane16 & 8) << 28;
    const unsigned s4 = (unsigned)(lane16 & 4) << 29;
    const unsigned s2 = (unsigned)(lane16 & 2) << 30;
    const unsigned s1 = (unsigned)(lane16 & 1) << 31;
    const unsigned sC = s8 ^ s4;
    const unsigned sE = sC ^ s2;
    const unsigned sF = sE ^ s1;

    // ---- lane-side encoding product over qubits 4..7 ----
    f2 P = enc_sel(th[4], ph[4], (lane16 & 8) != 0);
    P = cmul2(P, enc_sel(th[5], ph[5], (lane16 & 4) != 0));
    P = cmul2(P, enc_sel(th[6], ph[6], (lane16 & 2) != 0));
    P = cmul2(P, enc_sel(th[7], ph[7], (lane16 & 1) != 0));

    // ---- register-side partial products m01 (qubits 0,1), m23 (qubits 2,3) ----
    f2 m01[4], m23[4];
    {
        float s0, c0, sp0, cp0, s1_, c1_, sp1, cp1;
        __sincosf(th[0]*0.5f, &s0, &c0); __sincosf(ph[0]*0.5f, &sp0, &cp0);
        __sincosf(th[1]*0.5f, &s1_, &c1_); __sincosf(ph[1]*0.5f, &sp1, &cp1);
        const f2 A0={c0*cp0,-c0*sp0}, A1={s0*cp0,s0*sp0};
        const f2 B0={c1_*cp1,-c1_*sp1}, B1={s1_*cp1,s1_*sp1};
        #pragma unroll
        for (int a = 0; a < 4; ++a)
            m01[a] = cmul2((a & 2) ? A1 : A0, (a & 1) ? B1 : B0);
        __sincosf(th[2]*0.5f, &s0, &c0); __sincosf(ph[2]*0.5f, &sp0, &cp0);
        __sincosf(th[3]*0.5f, &s1_, &c1_); __sincosf(ph[3]*0.5f, &sp1, &cp1);
        const f2 C0={c0*cp0,-c0*sp0}, C1={s0*cp0,s0*sp0};
        const f2 D0={c1_*cp1,-c1_*sp1}, D1={s1_*cp1,s1_*sp1};
        #pragma unroll
        for (int a = 0; a < 4; ++a)
            m23[a] = cmul2((a & 2) ? C1 : C0, (a & 1) ? D1 : D0);
    }

    // ---- IsingZZ reduction: J[28] -> c01..c23, Q0..Q3, LL ----
    float c01, c02, c03, c12, c13, c23, Q0, Q1, Q2, Q3, LL;
    {
        const float4* J4 = reinterpret_cast<const float4*>(jup + (size_t)b * 28);
        const float z4 = (lane16 & 8) ? -1.f : 1.f;
        const float z5 = (lane16 & 4) ? -1.f : 1.f;
        const float z6 = (lane16 & 2) ? -1.f : 1.f;
        const float z7 = (lane16 & 1) ? -1.f : 1.f;
        const float4 x0 = J4[0], x1 = J4[1], x2 = J4[2], x3 = J4[3];
        const float4 x4 = J4[4], x5 = J4[5], x6 = J4[6];
        c01 = x0.x; c02 = x0.y; c03 = x0.z;
        Q0  = x0.w*z4 + x1.x*z5 + x1.y*z6 + x1.z*z7;
        c12 = x1.w; c13 = x2.x;
        Q1  = x2.y*z4 + x2.z*z5 + x2.w*z6 + x3.x*z7;
        c23 = x3.y;
        Q2  = x3.z*z4 + x3.w*z5 + x4.x*z6 + x4.y*z7;
        Q3  = x4.z*z4 + x4.w*z5 + x5.x*z6 + x5.y*z7;
        LL  = x5.z*(z4*z5) + x5.w*(z4*z6) + x6.x*(z4*z7)
            + x6.y*(z5*z6) + x6.z*(z5*z7) + x6.w*(z6*z7);
    }

    // ---- init amplitudes: product state x Ising phase ----
    f2 s[16];
    constexpr float HPI = 1.5707963267948966f;
    #pragma unroll
    for (int j = 0; j < 16; ++j) {
        f2 u = cmul2(cmul2(m01[j >> 2], m23[j & 3]), P);
        float S = LL;
        S += ((__builtin_popcount(j & 0xC) & 1) ? -c01 : c01);
        S += ((__builtin_popcount(j & 0xA) & 1) ? -c02 : c02);
        S += ((__builtin_popcount(j & 0x9) & 1) ? -c03 : c03);
        S += ((__builtin_popcount(j & 0x6) & 1) ? -c12 : c12);
        S += ((__builtin_popcount(j & 0x5) & 1) ? -c13 : c13);
        S += ((__builtin_popcount(j & 0x3) & 1) ? -c23 : c23);
        S += ((j & 8) ? -Q0 : Q0);
        S += ((j & 4) ? -Q1 : Q1);
        S += ((j & 2) ? -Q2 : Q2);
        S += ((j & 1) ? -Q3 : Q3);
        float se, ce;
        __sincosf(-HPI * S, &se, &ce);
        s[j] = cmul2(u, (f2){ce, se});
    }

    // ---- layer-0 Rot gates (A = I): v = u = e_p, p = 7-k ----
    ROT0(0, 0x8, 0x0, 0x8, 0u);
    ROT0(1, 0x4, 0x0, 0x4, 0u);
    ROT0(2, 0x2, 0x0, 0x2, 0u);
    ROT0(3, 0x1, 0x0, 0x1, 0u);
    ROT0(4, 0x0, 0x8, 0x0, s8);
    ROT0(5, 0x0, 0x4, 0x0, s4);
    ROT0(6, 0x0, 0x2, 0x0, s2);
    ROT0(7, 0x0, 0x1, 0x0, s1);

    // ---- layer-0 CNOT ring folded into relabeling; RENC(k)+ROT(1,k) fused ----
    FUSED(0, 0xC, 0x0, 0x7, sF);
    FUSED(1, 0x6, 0x0, 0xC, 0u);
    FUSED(2, 0x3, 0x0, 0xE, 0u);
    FUSED(3, 0x1, 0x8, 0xF, 0u);
    FUSED(4, 0x0, 0xC, 0xF, s8);
    FUSED(5, 0x0, 0x6, 0xF, sC);
    FUSED(6, 0x0, 0x3, 0xF, sE);
    FUSED(7, 0xC, 0x1, 0xF, sF);

    // layer-1 CNOT ring folded into readout signs (final A rows, verified R2)
    // ---- readout: probs, 16-point WHT over register index, lane signs ----
    float p[16];
    #pragma unroll
    for (int j = 0; j < 16; ++j) p[j] = fmaf(s[j].y, s[j].y, s[j].x * s[j].x);
    #pragma unroll
    for (int st = 1; st < 16; st <<= 1) {
        #pragma unroll
        for (int j = 0; j < 16; ++j) {
            if ((j & st) != 0) continue;
            const float a = p[j], bb = p[j | st];
            p[j] = a + bb;  p[j | st] = a - bb;
        }
    }
    float o[8];
    o[0] = (__popc(lane16 & 0x6) & 1) ? -p[0xE] : p[0xE];
    o[1] = (__popc(lane16 & 0x3) & 1) ? -p[0xF] : p[0xF];
    o[2] = (__popc(lane16 & 0xF) & 1) ? -p[0x9] : p[0x9];
    o[3] = p[0x3];
    o[4] = (__popc(lane16 & 0x7) & 1) ? -p[0x6] : p[0x6];
    o[5] = (__popc(lane16 & 0xC) & 1) ? -p[0xC] : p[0xC];
    o[6] = (__popc(lane16 & 0x9) & 1) ? -p[0x9] : p[0x9];
    o[7] = (__popc(lane16 & 0x3) & 1) ? -p[0x3] : p[0x3];

    #pragma unroll
    for (int m = 1; m <= 8; m <<= 1) {
        #pragma unroll
        for (int q = 0; q < 8; ++q) o[q] += __shfl_xor(o[q], m, 64);
    }

    if (lane16 == 0 && bq < Btot) {
        float4* op = reinterpret_cast<float4*>(out + (size_t)bq * 8);
        op[0] = make_float4(o[0], o[1], o[2], o[3]);
        op[1] = make_float4(o[4], o[5], o[6], o[7]);
    }
}

extern "C" void kernel_launch(void* const* d_in, const int* in_sizes, int n_in,
                              void* d_out, int out_size, void* d_ws, size_t ws_size,
                              hipStream_t stream) {
    const float* theta = (const float*)d_in[0];
    const float* phi   = (const float*)d_in[1];
    const float* jup   = (const float*)d_in[2];
    const float* w     = (const float*)d_in[3];
    float* out   = (float*)d_out;
    float* gates = (float*)d_ws;                 // 16 gates x 4 floats = 256 B

    const int B = in_sizes[0] / 8;               // 16384
    hipLaunchKernelGGL(prep_gates, dim3(1), dim3(64), 0, stream, w, gates);

    const int blocks = (B + 3) / 4;              // 4096: one wave / block
    hipLaunchKernelGGL(vqc_kernel, dim3(blocks), dim3(64), 0, stream,
                       theta, phi, jup, gates, out, B);
}